// Round 11
// baseline (24.709 us; speedup 1.0000x reference)
//
#include <hip/hip_runtime.h>

// PDE2DReservoir — ONE dispatch, ZERO cross-block deps.
// measured[m] = sum_j vals_j * K(m - p_j); K even in both args, support <= 63.
// Each block independently materializes the 64x64 quadrant Kq[|dx|][|dy|] in
// LDS via: Horner Khat (deg-63, 65x65 folded modes) -> two separable cosine
// passes (Chebyshev recurrences, 8 outputs share each float4 khf/B read),
// wx=64 / wy=64 modes folded analytically (cos(64*theta_u) = (-1)^u).
// Then the R8-validated 4096x16 scan: each hit = ONE LDS read of Kq.
// R8's mistake (28.8us): per-hit 4225-mode dots, LDS-BW bound. Fixed here.

#define N_INJ   4096
#define ND      128
#define NM      65
#define STEPS   64
#define WRAP_M  4095
#define NB      256              // independent blocks, 1 per CU
#define NT      512
#define MPB     16               // measurements per block
#define KST     68               // khf row stride (16B-aligned rows)
#define BST     68               // B row stride

__global__ __launch_bounds__(NT) void fused_all(const float* __restrict__ u_t,
                                                const float* __restrict__ scales,
                                                const int* __restrict__ dims,
                                                const int* __restrict__ iix,
                                                const int* __restrict__ iiy,
                                                const int* __restrict__ mix,
                                                const int* __restrict__ miy,
                                                float* __restrict__ out) {
    const int b = blockIdx.x;
    const int t = threadIdx.x;

    __shared__ float ctab[ND];         // cos(2*pi*i/128)
    __shared__ float coeff[STEPS];     // DT * sin(2*pi*s/64)
    __shared__ float khf[NM * KST];    // weighted Khat [wx][wy]   (17.3 KB)
    __shared__ float Bm[64 * BST];     // pass-1 out   [ay][wx<64] (17.0 KB)
    __shared__ float Rv[64];           // R(u) = sum_{wx<64} khf[wx][64] cos(wx*u)
    __shared__ float Kq[64 * 64];      // Green quadrant           (16.0 KB)
    __shared__ float smacc[MPB];

    if (t < ND)    ctab[t]  = cosf(0.049087385212340517f * (float)t);
    if (t < STEPS) coeff[t] = 0.001f * sinf(0.09817477042468103f * (float)t);
    if (t < MPB)   smacc[t] = 0.f;
    __syncthreads();

    // ---- Horner: khf[wx][wy] = w * sum_s coeff[s] * lam^(63-s), 9/thread ----
    {
        float hh[9], lam[9];
#pragma unroll
        for (int k = 0; k < 9; ++k) {
            int e = t + NT * k; if (e >= NM * NM) e = NM * NM - 1;
            const int wx = e / NM, wy = e - wx * NM;
            lam[k] = 0.9f + 0.05f * (ctab[wx] + ctab[wy]);
            hh[k]  = coeff[0];
        }
#pragma unroll 9
        for (int s = 1; s < STEPS; ++s) {
            const float cs = coeff[s];
#pragma unroll
            for (int k = 0; k < 9; ++k) hh[k] = fmaf(hh[k], lam[k], cs);
        }
#pragma unroll
        for (int k = 0; k < 9; ++k) {
            const int e = t + NT * k;
            if (e < NM * NM) {
                const int wx = e / NM, wy = e - wx * NM;
                const float w = ((wx == 0 || wx == 64) ? 1.f : 2.f)
                              * ((wy == 0 || wy == 64) ? 1.f : 2.f) * (1.f / 16384.f);
                khf[wx * KST + wy] = hh[k] * w;
            }
        }
    }
    __syncthreads();

    // ---- pass 1: Bm[ay][wx] = sum_{wy<64} khf[wx][wy] cos(wy*theta_ay) ----
    {
        const int wx  = t >> 3;          // 0..63 (8 lanes per wx -> b128 bcast)
        const int ay0 = t & 7;
        float cw[8], cm[8], tc[8], ac[8];
#pragma unroll
        for (int i = 0; i < 8; ++i) {
            const float c1 = ctab[ay0 + 8 * i];
            tc[i] = 2.f * c1; cw[i] = 1.f; cm[i] = c1; ac[i] = 0.f;
        }
        const float4* __restrict__ krow =
            reinterpret_cast<const float4*>(&khf[wx * KST]);
#pragma unroll
        for (int q = 0; q < 16; ++q) {
            const float4 k4 = krow[q];
            const float kv[4] = {k4.x, k4.y, k4.z, k4.w};
#pragma unroll
            for (int c = 0; c < 4; ++c) {
#pragma unroll
                for (int i = 0; i < 8; ++i) {
                    ac[i] = fmaf(kv[c], cw[i], ac[i]);
                    const float nx = fmaf(tc[i], cw[i], -cm[i]);
                    cm[i] = cw[i]; cw[i] = nx;
                }
            }
        }
#pragma unroll
        for (int i = 0; i < 8; ++i) Bm[(ay0 + 8 * i) * BST + wx] = ac[i];

        if (t < 64) {                    // R(u), 64 dots of length 64
            float acc = 0.f;
#pragma unroll 8
            for (int wx2 = 0; wx2 < 64; ++wx2)
                acc = fmaf(khf[wx2 * KST + 64], ctab[(wx2 * t) & 127], acc);
            Rv[t] = acc;
        }
    }
    __syncthreads();

    // ---- pass 2: Kq[ax][ay] = S + (-1)^ay R(ax) + (-1)^ax R(ay) + (-1)^(ax+ay) k64
    {
        const int ay  = t >> 3;
        const int ax0 = t & 7;
        float cw[8], cm[8], tc[8], ac[8];
#pragma unroll
        for (int i = 0; i < 8; ++i) {
            const float c1 = ctab[ax0 + 8 * i];
            tc[i] = 2.f * c1; cw[i] = 1.f; cm[i] = c1; ac[i] = 0.f;
        }
        const float4* __restrict__ brow =
            reinterpret_cast<const float4*>(&Bm[ay * BST]);
#pragma unroll
        for (int q = 0; q < 16; ++q) {
            const float4 k4 = brow[q];
            const float kv[4] = {k4.x, k4.y, k4.z, k4.w};
#pragma unroll
            for (int c = 0; c < 4; ++c) {
#pragma unroll
                for (int i = 0; i < 8; ++i) {
                    ac[i] = fmaf(kv[c], cw[i], ac[i]);
                    const float nx = fmaf(tc[i], cw[i], -cm[i]);
                    cm[i] = cw[i]; cw[i] = nx;
                }
            }
        }
        const float k64 = khf[64 * KST + 64];
        const float ry  = Rv[ay];
        const float sy  = (ay & 1) ? -1.f : 1.f;
#pragma unroll
        for (int i = 0; i < 8; ++i) {
            const int ax   = ax0 + 8 * i;
            const float sx = (ax & 1) ? -1.f : 1.f;
            Kq[ax * 64 + ay] = ac[i] + sy * Rv[ax] + sx * ry + sx * sy * k64;
        }
    }
    __syncthreads();

    // ---- scan: 8 injections/thread x 16 measurements; hit = one LDS read ----
    int mx[MPB], my[MPB];
#pragma unroll
    for (int i = 0; i < MPB; ++i) {     // block-uniform -> scalar loads
        mx[i] = mix[(b << 4) + i];
        my[i] = miy[(b << 4) + i];
    }
#pragma unroll
    for (int jj = 0; jj < N_INJ / NT; ++jj) {
        const int j   = jj * NT + t;
        const float v = scales[j] * u_t[dims[j]];
        const int ix  = iix[j];
        const int iy  = iiy[j];
#pragma unroll
        for (int i = 0; i < MPB; ++i) {
            const int a  = (mx[i] - ix) & WRAP_M;
            const int c  = (my[i] - iy) & WRAP_M;
            const int ax = min(a, 4096 - a);
            const int ay = min(c, 4096 - c);
            if (ax < 64 && ay < 64)
                atomicAdd(&smacc[i], v * Kq[ax * 64 + ay]);
        }
    }
    __syncthreads();
    if (t < MPB) out[(b << 4) + t] = smacc[t];
}

extern "C" void kernel_launch(void* const* d_in, const int* in_sizes, int n_in,
                              void* d_out, int out_size, void* d_ws, size_t ws_size,
                              hipStream_t stream) {
    const float* u_t        = (const float*)d_in[0];
    const float* inj_scales = (const float*)d_in[1];
    const int*   inj_dims   = (const int*)d_in[2];
    const int*   inj_ix     = (const int*)d_in[3];
    const int*   inj_iy     = (const int*)d_in[4];
    const int*   meas_ix    = (const int*)d_in[5];
    const int*   meas_iy    = (const int*)d_in[6];
    float*       out        = (float*)d_out;

    hipLaunchKernelGGL(fused_all, dim3(NB), dim3(NT), 0, stream,
                       u_t, inj_scales, inj_dims, inj_ix, inj_iy,
                       meas_ix, meas_iy, out);
}

// Round 12
// 20.681 us; speedup vs baseline: 1.1948x; 1.1948x over previous
//
#include <hip/hip_runtime.h>
#include <utility>
#include <cstddef>

// PDE2DReservoir — compile-time Green's function + one tiny dispatch.
// measured[m] = sum_j vals_j * K(m - p_j); K is a FIXED 127-radius stencil
// (independent of all inputs), even in both arguments. We evaluate the
// R5-validated spectral construction entirely in constexpr double math and
// bake the 64x64 quadrant Kq[|dx|][|dy|] into the device image.
// GPU work left: bin 4096 injections into a 64x64 LDS grid (counting sort),
// then each measurement gathers from its 3x3 neighbor bins (~9 candidates).
// Rounds 3/5/6: no intra-kernel grid sync. Rounds 7-11: fewer/leaner nodes win.

#define WRAP_M  4095
#define N_INJ   4096

// ---------------- constexpr spectral build (double precision) ----------------
namespace ck {

constexpr double PI_ = 3.14159265358979323846264338327950288;

constexpr double tcos(double x) {            // |x| <= pi/4
    const double x2 = x * x;
    double term = 1.0, sum = 1.0;
    for (int k = 1; k <= 9; ++k) { term *= -x2 / double((2*k-1)*(2*k)); sum += term; }
    return sum;
}
constexpr double tsin(double x) {            // |x| <= pi/4
    const double x2 = x * x;
    double term = x, sum = x;
    for (int k = 1; k <= 9; ++k) { term *= -x2 / double((2*k)*(2*k+1)); sum += term; }
    return sum;
}
constexpr double ang(int i) { return (2.0 * PI_ / 128.0) * i; }   // i in [0,16]

constexpr double c128(int k) {               // cos(2*pi*k/128), exact reduction
    k &= 127;
    double sgn = 1.0;
    if (k > 64) k = 128 - k;
    if (k > 32) { sgn = -1.0; k = 64 - k; }
    return (k > 16) ? sgn * tsin(ang(32 - k)) : sgn * tcos(ang(k));
}
constexpr double s128(int k) {               // sin(2*pi*k/128)
    k &= 127;
    double sgn = 1.0;
    if (k >= 64) { sgn = -1.0; k -= 64; }
    if (k > 32) k = 64 - k;
    return (k > 16) ? sgn * tcos(ang(32 - k)) : sgn * tsin(ang(k));
}

struct A128d { double v[128]; };
struct A64d  { double v[64];  };
struct A65d  { double v[65];  };

constexpr A128d mk_ct() { A128d r{}; for (int i = 0; i < 128; ++i) r.v[i] = c128(i); return r; }
constexpr A128d CT = mk_ct();
constexpr A64d mk_cf() { A64d r{}; for (int s = 0; s < 64; ++s) r.v[s] = 0.001 * s128(2 * s); return r; }
constexpr A64d CF = mk_cf();                 // DT * sin(2*pi*s/64)

// Khat(wx,wy) = w(wx)w(wy)/16384 * sum_s CF[s] * lam^(63-s), lam = 0.9+0.05(cx+cy)
constexpr A65d khf_row(int wx) {
    A65d r{};
    const double cx  = CT.v[wx];
    const double wxw = (wx == 0 || wx == 64) ? 1.0 : 2.0;
    for (int wy = 0; wy < 65; ++wy) {
        const double lam = 0.9 + 0.05 * (cx + CT.v[wy]);
        double h = CF.v[0];
        for (int s = 1; s < 64; ++s) h = h * lam + CF.v[s];
        r.v[wy] = h * wxw * ((wy == 0 || wy == 64) ? 1.0 : 2.0) * (1.0 / 16384.0);
    }
    return r;
}
template<int WX> inline constexpr A65d KHF_ROW = khf_row(WX);
struct KHF_T { A65d r[65]; };
template<std::size_t... I>
constexpr KHF_T mk_khf(std::index_sequence<I...>) { return KHF_T{{ KHF_ROW<(int)I>... }}; }
constexpr KHF_T KHF = mk_khf(std::make_index_sequence<65>{});

// pass 1: B[ay][wx] = sum_wy KHF[wx][wy] * cos(wy*ay)
constexpr A65d b_row(int ay) {
    A65d r{};
    for (int wx = 0; wx < 65; ++wx) {
        double acc = 0.0;
        for (int wy = 0; wy < 65; ++wy) acc += KHF.r[wx].v[wy] * CT.v[(wy * ay) & 127];
        r.v[wx] = acc;
    }
    return r;
}
template<int AY> inline constexpr A65d B_ROW = b_row(AY);
struct BM_T { A65d r[64]; };
template<std::size_t... I>
constexpr BM_T mk_bm(std::index_sequence<I...>) { return BM_T{{ B_ROW<(int)I>... }}; }
constexpr BM_T BM = mk_bm(std::make_index_sequence<64>{});

// pass 2: Kq[ax][ay] = sum_wx B[ay][wx] * cos(wx*ax), cast to float
struct F64f { float v[64]; };
constexpr F64f kq_row(int ax) {
    F64f r{};
    for (int ay = 0; ay < 64; ++ay) {
        double acc = 0.0;
        for (int wx = 0; wx < 65; ++wx) acc += BM.r[ay].v[wx] * CT.v[(wx * ax) & 127];
        r.v[ay] = (float)acc;
    }
    return r;
}
template<int AX> inline constexpr F64f KQ_ROW = kq_row(AX);
struct KQ_T { F64f r[64]; };
template<std::size_t... I>
constexpr KQ_T mk_kq(std::index_sequence<I...>) { return KQ_T{{ KQ_ROW<(int)I>... }}; }

}  // namespace ck

__device__ constexpr ck::KQ_T KQ = ck::mk_kq(std::make_index_sequence<64>{});

// ---------------- the single kernel ----------------
// 32 blocks x 256 threads. Each block: LDS counting-sort of all 4096
// injections into 64x64 bins, then 128 threads resolve one measurement each
// from the 3x3 neighbor bins. Post-scatter, cnt[bin] = END of bin;
// start(bin) = bin ? cnt[bin-1] : 0 (bins globally contiguous).
__global__ __launch_bounds__(256) void fused(const float* __restrict__ u_t,
                                             const float* __restrict__ scales,
                                             const int* __restrict__ dims,
                                             const int* __restrict__ iix,
                                             const int* __restrict__ iiy,
                                             const int* __restrict__ mix,
                                             const int* __restrict__ miy,
                                             float* __restrict__ out) {
    const int b = blockIdx.x;
    const int t = threadIdx.x;

    __shared__ int   cnt[4096];
    __shared__ int   spack[4096];
    __shared__ float sval[4096];
    __shared__ int   wtot[4];

    for (int k = t; k < 4096; k += 256) cnt[k] = 0;
    __syncthreads();

    // histogram
    for (int j = t; j < N_INJ; j += 256)
        atomicAdd(&cnt[((iix[j] >> 6) << 6) | (iiy[j] >> 6)], 1);
    __syncthreads();

    // prefix scan (R10-validated): cnt <- bin starts (scatter cursors)
    int loc[16], s = 0;
#pragma unroll
    for (int k = 0; k < 16; ++k) { loc[k] = cnt[t * 16 + k]; s += loc[k]; }
    const int lane = t & 63, wv = t >> 6;
    int x = s;
#pragma unroll
    for (int d = 1; d < 64; d <<= 1) {
        const int y = __shfl_up(x, d, 64);
        if (lane >= d) x += y;
    }
    if (lane == 63) wtot[wv] = x;
    __syncthreads();                       // also orders loc reads vs writes below
    int run = x - s;
    for (int w = 0; w < wv; ++w) run += wtot[w];
#pragma unroll
    for (int k = 0; k < 16; ++k) { cnt[t * 16 + k] = run; run += loc[k]; }
    __syncthreads();

    // scatter (vals computed inline)
    for (int j = t; j < N_INJ; j += 256) {
        const int ix  = iix[j], iy = iiy[j];
        const int pos = atomicAdd(&cnt[((ix >> 6) << 6) | (iy >> 6)], 1);
        spack[pos] = (ix << 12) | iy;
        sval[pos]  = scales[j] * u_t[dims[j]];
    }
    __syncthreads();

    // measure: one thread per measurement, 3x3 neighbor bins
    if (t < 128) {
        const int m  = (b << 7) + t;
        const int mx = mix[m];
        const int my = miy[m];
        const int axlo = ((mx - 63) & WRAP_M) >> 6;
        const int aylo = ((my - 63) & WRAP_M) >> 6;
        float acc = 0.f;
#pragma unroll
        for (int r2 = 0; r2 < 3; ++r2) {
            const int base = ((axlo + r2) & 63) << 6;
            int s0[2], s1[2], nseg = 1;
            s0[0] = base + aylo;
            if (aylo <= 61) {
                s1[0] = base + aylo + 2;
            } else {                        // y-range wraps the bin row
                s1[0] = base + 63;
                s0[1] = base; s1[1] = base + (aylo - 62);
                nseg = 2;
            }
            for (int sg = 0; sg < nseg; ++sg) {
                const int lo = s0[sg] ? cnt[s0[sg] - 1] : 0;
                const int hi = cnt[s1[sg]];
                for (int p = lo; p < hi; ++p) {
                    const int sp = spack[p];
                    const int a  = (mx - (sp >> 12)) & WRAP_M;
                    const int c  = (my - (sp & WRAP_M)) & WRAP_M;
                    if ((((a + 63) & WRAP_M) < 127) && (((c + 63) & WRAP_M) < 127)) {
                        const int ax = min(a, 4096 - a);
                        const int ay = min(c, 4096 - c);
                        acc += sval[p] * KQ.r[ax].v[ay];
                    }
                }
            }
        }
        out[m] = acc;
    }
}

extern "C" void kernel_launch(void* const* d_in, const int* in_sizes, int n_in,
                              void* d_out, int out_size, void* d_ws, size_t ws_size,
                              hipStream_t stream) {
    const float* u_t        = (const float*)d_in[0];
    const float* inj_scales = (const float*)d_in[1];
    const int*   inj_dims   = (const int*)d_in[2];
    const int*   inj_ix     = (const int*)d_in[3];
    const int*   inj_iy     = (const int*)d_in[4];
    const int*   meas_ix    = (const int*)d_in[5];
    const int*   meas_iy    = (const int*)d_in[6];
    float*       out        = (float*)d_out;

    hipLaunchKernelGGL(fused, dim3(32), dim3(256), 0, stream,
                       u_t, inj_scales, inj_dims, inj_ix, inj_iy,
                       meas_ix, meas_iy, out);
}

// Round 13
// 16.909 us; speedup vs baseline: 1.4613x; 1.2231x over previous
//
#include <hip/hip_runtime.h>
#include <utility>
#include <cstddef>

// PDE2DReservoir — compile-time Green's function + one tiny dispatch (lean).
// measured[m] = sum_j vals_j * K(m - p_j); K is a FIXED 127-radius stencil
// (input-independent), even in both args. K's 64x64 quadrant is evaluated at
// COMPILE TIME (constexpr double spectral build, R12-validated: absmax 1.7e-18)
// and baked into the device image.
// Runtime: 8 blocks x 1024 threads. Each block: register-staged LDS counting
// sort of the 4096 injections into 64x64 bins (4/thread), then threads 0..511
// resolve one measurement each from the 3x3 neighbor bins.
// Session ledger: ~18us is fixed graph-replay floor (R10 20.9 / R12 20.7 with
// ~3 vs ~2.7us kernels); this round shrinks the kernel residual ~2x.

#define WRAP_M  4095
#define N_INJ   4096

// ---------------- constexpr spectral build (double precision) ----------------
namespace ck {

constexpr double PI_ = 3.14159265358979323846264338327950288;

constexpr double tcos(double x) {            // |x| <= pi/4
    const double x2 = x * x;
    double term = 1.0, sum = 1.0;
    for (int k = 1; k <= 9; ++k) { term *= -x2 / double((2*k-1)*(2*k)); sum += term; }
    return sum;
}
constexpr double tsin(double x) {            // |x| <= pi/4
    const double x2 = x * x;
    double term = x, sum = x;
    for (int k = 1; k <= 9; ++k) { term *= -x2 / double((2*k)*(2*k+1)); sum += term; }
    return sum;
}
constexpr double ang(int i) { return (2.0 * PI_ / 128.0) * i; }   // i in [0,16]

constexpr double c128(int k) {               // cos(2*pi*k/128), exact reduction
    k &= 127;
    double sgn = 1.0;
    if (k > 64) k = 128 - k;
    if (k > 32) { sgn = -1.0; k = 64 - k; }
    return (k > 16) ? sgn * tsin(ang(32 - k)) : sgn * tcos(ang(k));
}
constexpr double s128(int k) {               // sin(2*pi*k/128)
    k &= 127;
    double sgn = 1.0;
    if (k >= 64) { sgn = -1.0; k -= 64; }
    if (k > 32) k = 64 - k;
    return (k > 16) ? sgn * tcos(ang(32 - k)) : sgn * tsin(ang(k));
}

struct A128d { double v[128]; };
struct A64d  { double v[64];  };
struct A65d  { double v[65];  };

constexpr A128d mk_ct() { A128d r{}; for (int i = 0; i < 128; ++i) r.v[i] = c128(i); return r; }
constexpr A128d CT = mk_ct();
constexpr A64d mk_cf() { A64d r{}; for (int s = 0; s < 64; ++s) r.v[s] = 0.001 * s128(2 * s); return r; }
constexpr A64d CF = mk_cf();                 // DT * sin(2*pi*s/64)

constexpr A65d khf_row(int wx) {
    A65d r{};
    const double cx  = CT.v[wx];
    const double wxw = (wx == 0 || wx == 64) ? 1.0 : 2.0;
    for (int wy = 0; wy < 65; ++wy) {
        const double lam = 0.9 + 0.05 * (cx + CT.v[wy]);
        double h = CF.v[0];
        for (int s = 1; s < 64; ++s) h = h * lam + CF.v[s];
        r.v[wy] = h * wxw * ((wy == 0 || wy == 64) ? 1.0 : 2.0) * (1.0 / 16384.0);
    }
    return r;
}
template<int WX> inline constexpr A65d KHF_ROW = khf_row(WX);
struct KHF_T { A65d r[65]; };
template<std::size_t... I>
constexpr KHF_T mk_khf(std::index_sequence<I...>) { return KHF_T{{ KHF_ROW<(int)I>... }}; }
constexpr KHF_T KHF = mk_khf(std::make_index_sequence<65>{});

constexpr A65d b_row(int ay) {
    A65d r{};
    for (int wx = 0; wx < 65; ++wx) {
        double acc = 0.0;
        for (int wy = 0; wy < 65; ++wy) acc += KHF.r[wx].v[wy] * CT.v[(wy * ay) & 127];
        r.v[wx] = acc;
    }
    return r;
}
template<int AY> inline constexpr A65d B_ROW = b_row(AY);
struct BM_T { A65d r[64]; };
template<std::size_t... I>
constexpr BM_T mk_bm(std::index_sequence<I...>) { return BM_T{{ B_ROW<(int)I>... }}; }
constexpr BM_T BM = mk_bm(std::make_index_sequence<64>{});

struct F64f { float v[64]; };
constexpr F64f kq_row(int ax) {
    F64f r{};
    for (int ay = 0; ay < 64; ++ay) {
        double acc = 0.0;
        for (int wx = 0; wx < 65; ++wx) acc += BM.r[ay].v[wx] * CT.v[(wx * ax) & 127];
        r.v[ay] = (float)acc;
    }
    return r;
}
template<int AX> inline constexpr F64f KQ_ROW = kq_row(AX);
struct KQ_T { F64f r[64]; };
template<std::size_t... I>
constexpr KQ_T mk_kq(std::index_sequence<I...>) { return KQ_T{{ KQ_ROW<(int)I>... }}; }

}  // namespace ck

__device__ constexpr ck::KQ_T KQ = ck::mk_kq(std::make_index_sequence<64>{});

// ---------------- the single kernel ----------------
__global__ __launch_bounds__(1024) void fused(const float* __restrict__ u_t,
                                              const float* __restrict__ scales,
                                              const int* __restrict__ dims,
                                              const int* __restrict__ iix,
                                              const int* __restrict__ iiy,
                                              const int* __restrict__ mix,
                                              const int* __restrict__ miy,
                                              float* __restrict__ out) {
    const int b = blockIdx.x;
    const int t = threadIdx.x;

    __shared__ int   cnt[4096];
    __shared__ int   spack[4096];
    __shared__ float sval[4096];
    __shared__ int   wtot[16];

    for (int k = t; k < 4096; k += 1024) cnt[k] = 0;
    __syncthreads();

    // stage 4 injections/thread in registers + histogram
    int pk[4], pb[4];
    float pv[4];
#pragma unroll
    for (int i = 0; i < 4; ++i) {
        const int j  = t + 1024 * i;          // coalesced
        const int ix = iix[j], iy = iiy[j];
        pk[i] = (ix << 12) | iy;
        pb[i] = ((ix >> 6) << 6) | (iy >> 6);
        pv[i] = scales[j] * u_t[dims[j]];
        atomicAdd(&cnt[pb[i]], 1);
    }
    __syncthreads();

    // two-level exclusive prefix scan over 4096 bins (4 bins/thread)
    int loc[4], s = 0;
#pragma unroll
    for (int k = 0; k < 4; ++k) { loc[k] = cnt[t * 4 + k]; s += loc[k]; }
    const int lane = t & 63, wv = t >> 6;
    int x = s;
#pragma unroll
    for (int d = 1; d < 64; d <<= 1) {
        const int y = __shfl_up(x, d, 64);
        if (lane >= d) x += y;
    }
    if (lane == 63) wtot[wv] = x;
    __syncthreads();                          // also orders loc reads vs writes
    int run = x - s;
    for (int w = 0; w < wv; ++w) run += wtot[w];
#pragma unroll
    for (int k = 0; k < 4; ++k) { cnt[t * 4 + k] = run; run += loc[k]; }
    __syncthreads();

    // scatter from registers
#pragma unroll
    for (int i = 0; i < 4; ++i) {
        const int pos = atomicAdd(&cnt[pb[i]], 1);
        spack[pos] = pk[i];
        sval[pos]  = pv[i];
    }
    __syncthreads();
    // post-scatter: cnt[bin] = END of bin; start = bin ? cnt[bin-1] : 0

    // measure: threads 0..511, one measurement each, 3x3 neighbor bins
    if (t < 512) {
        const int m  = (b << 9) + t;
        const int mx = mix[m];
        const int my = miy[m];
        const int axlo = ((mx - 63) & WRAP_M) >> 6;
        const int aylo = ((my - 63) & WRAP_M) >> 6;
        float acc = 0.f;
#pragma unroll
        for (int r2 = 0; r2 < 3; ++r2) {
            const int base = ((axlo + r2) & 63) << 6;
            int s0[2], s1[2], nseg = 1;
            s0[0] = base + aylo;
            if (aylo <= 61) {
                s1[0] = base + aylo + 2;
            } else {                          // y-range wraps the bin row
                s1[0] = base + 63;
                s0[1] = base; s1[1] = base + (aylo - 62);
                nseg = 2;
            }
            for (int sg = 0; sg < nseg; ++sg) {
                const int lo = s0[sg] ? cnt[s0[sg] - 1] : 0;
                const int hi = cnt[s1[sg]];
                for (int p = lo; p < hi; ++p) {
                    const int sp = spack[p];
                    const int a  = (mx - (sp >> 12)) & WRAP_M;
                    const int c  = (my - (sp & WRAP_M)) & WRAP_M;
                    if ((((a + 63) & WRAP_M) < 127) && (((c + 63) & WRAP_M) < 127)) {
                        const int ax = min(a, 4096 - a);
                        const int ay = min(c, 4096 - c);
                        acc += sval[p] * KQ.r[ax].v[ay];
                    }
                }
            }
        }
        out[m] = acc;
    }
}

extern "C" void kernel_launch(void* const* d_in, const int* in_sizes, int n_in,
                              void* d_out, int out_size, void* d_ws, size_t ws_size,
                              hipStream_t stream) {
    const float* u_t        = (const float*)d_in[0];
    const float* inj_scales = (const float*)d_in[1];
    const int*   inj_dims   = (const int*)d_in[2];
    const int*   inj_ix     = (const int*)d_in[3];
    const int*   inj_iy     = (const int*)d_in[4];
    const int*   meas_ix    = (const int*)d_in[5];
    const int*   meas_iy    = (const int*)d_in[6];
    float*       out        = (float*)d_out;

    hipLaunchKernelGGL(fused, dim3(8), dim3(1024), 0, stream,
                       u_t, inj_scales, inj_dims, inj_ix, inj_iy,
                       meas_ix, meas_iy, out);
}

// Round 14
// 16.342 us; speedup vs baseline: 1.5120x; 1.0347x over previous
//
#include <hip/hip_runtime.h>
#include <utility>
#include <cstddef>

// PDE2DReservoir — compile-time Green's function + one tiny dispatch (leaner).
// measured[m] = sum_j vals_j * K(m - p_j); K is a FIXED 127-radius stencil
// (input-independent), even in both args; its 64x64 quadrant is evaluated at
// COMPILE TIME (constexpr double spectral build, validated absmax 1.7e-18).
// Runtime (16 blocks x 1024 thr): register-staged LDS counting sort of 4096
// injections into 64x64 bins — histogram's atomicAdd return IS the in-bin
// rank, so the scatter needs NO atomics — then 256 threads/block resolve one
// measurement each from the 3x3 neighbor bins.
// Ledger: R12 20.7 -> R13 16.9 (lean sort) -> this: -4096 LDS atomics/block,
// int4-vectorized staging, measure coords hoisted above all barriers.

#define WRAP_M  4095
#define N_INJ   4096

// ---------------- constexpr spectral build (double precision) ----------------
namespace ck {

constexpr double PI_ = 3.14159265358979323846264338327950288;

constexpr double tcos(double x) {            // |x| <= pi/4
    const double x2 = x * x;
    double term = 1.0, sum = 1.0;
    for (int k = 1; k <= 9; ++k) { term *= -x2 / double((2*k-1)*(2*k)); sum += term; }
    return sum;
}
constexpr double tsin(double x) {            // |x| <= pi/4
    const double x2 = x * x;
    double term = x, sum = x;
    for (int k = 1; k <= 9; ++k) { term *= -x2 / double((2*k)*(2*k+1)); sum += term; }
    return sum;
}
constexpr double ang(int i) { return (2.0 * PI_ / 128.0) * i; }   // i in [0,16]

constexpr double c128(int k) {               // cos(2*pi*k/128), exact reduction
    k &= 127;
    double sgn = 1.0;
    if (k > 64) k = 128 - k;
    if (k > 32) { sgn = -1.0; k = 64 - k; }
    return (k > 16) ? sgn * tsin(ang(32 - k)) : sgn * tcos(ang(k));
}
constexpr double s128(int k) {               // sin(2*pi*k/128)
    k &= 127;
    double sgn = 1.0;
    if (k >= 64) { sgn = -1.0; k -= 64; }
    if (k > 32) k = 64 - k;
    return (k > 16) ? sgn * tcos(ang(32 - k)) : sgn * tsin(ang(k));
}

struct A128d { double v[128]; };
struct A64d  { double v[64];  };
struct A65d  { double v[65];  };

constexpr A128d mk_ct() { A128d r{}; for (int i = 0; i < 128; ++i) r.v[i] = c128(i); return r; }
constexpr A128d CT = mk_ct();
constexpr A64d mk_cf() { A64d r{}; for (int s = 0; s < 64; ++s) r.v[s] = 0.001 * s128(2 * s); return r; }
constexpr A64d CF = mk_cf();                 // DT * sin(2*pi*s/64)

constexpr A65d khf_row(int wx) {
    A65d r{};
    const double cx  = CT.v[wx];
    const double wxw = (wx == 0 || wx == 64) ? 1.0 : 2.0;
    for (int wy = 0; wy < 65; ++wy) {
        const double lam = 0.9 + 0.05 * (cx + CT.v[wy]);
        double h = CF.v[0];
        for (int s = 1; s < 64; ++s) h = h * lam + CF.v[s];
        r.v[wy] = h * wxw * ((wy == 0 || wy == 64) ? 1.0 : 2.0) * (1.0 / 16384.0);
    }
    return r;
}
template<int WX> inline constexpr A65d KHF_ROW = khf_row(WX);
struct KHF_T { A65d r[65]; };
template<std::size_t... I>
constexpr KHF_T mk_khf(std::index_sequence<I...>) { return KHF_T{{ KHF_ROW<(int)I>... }}; }
constexpr KHF_T KHF = mk_khf(std::make_index_sequence<65>{});

constexpr A65d b_row(int ay) {
    A65d r{};
    for (int wx = 0; wx < 65; ++wx) {
        double acc = 0.0;
        for (int wy = 0; wy < 65; ++wy) acc += KHF.r[wx].v[wy] * CT.v[(wy * ay) & 127];
        r.v[wx] = acc;
    }
    return r;
}
template<int AY> inline constexpr A65d B_ROW = b_row(AY);
struct BM_T { A65d r[64]; };
template<std::size_t... I>
constexpr BM_T mk_bm(std::index_sequence<I...>) { return BM_T{{ B_ROW<(int)I>... }}; }
constexpr BM_T BM = mk_bm(std::make_index_sequence<64>{});

struct F64f { float v[64]; };
constexpr F64f kq_row(int ax) {
    F64f r{};
    for (int ay = 0; ay < 64; ++ay) {
        double acc = 0.0;
        for (int wx = 0; wx < 65; ++wx) acc += BM.r[ay].v[wx] * CT.v[(wx * ax) & 127];
        r.v[ay] = (float)acc;
    }
    return r;
}
template<int AX> inline constexpr F64f KQ_ROW = kq_row(AX);
struct KQ_T { F64f r[64]; };
template<std::size_t... I>
constexpr KQ_T mk_kq(std::index_sequence<I...>) { return KQ_T{{ KQ_ROW<(int)I>... }}; }

}  // namespace ck

__device__ constexpr ck::KQ_T KQ = ck::mk_kq(std::make_index_sequence<64>{});

// ---------------- the single kernel ----------------
__global__ __launch_bounds__(1024) void fused(const float* __restrict__ u_t,
                                              const float* __restrict__ scales,
                                              const int* __restrict__ dims,
                                              const int* __restrict__ iix,
                                              const int* __restrict__ iiy,
                                              const int* __restrict__ mix,
                                              const int* __restrict__ miy,
                                              float* __restrict__ out) {
    const int b = blockIdx.x;
    const int t = threadIdx.x;

    __shared__ int   cnt[4097];          // counts -> starts; cnt[4096]=N_INJ
    __shared__ int   spack[4096];
    __shared__ float sval[4096];
    __shared__ int   wtot[16];

    // measurement coords: hoisted above all barriers (overlap sort latency)
    int mx = 0, my = 0;
    if (t < 256) {
        const int m = (b << 8) + t;
        mx = mix[m];
        my = miy[m];
    }

    for (int k = t; k < 4096; k += 1024) cnt[k] = 0;

    // vectorized staging: j = 4t..4t+3 (coalesced dwordx4)
    const int4   vix = reinterpret_cast<const int4*>(iix)[t];
    const int4   viy = reinterpret_cast<const int4*>(iiy)[t];
    const int4   vdm = reinterpret_cast<const int4*>(dims)[t];
    const float4 vsc = reinterpret_cast<const float4*>(scales)[t];
    const int ixr[4] = {vix.x, vix.y, vix.z, vix.w};
    const int iyr[4] = {viy.x, viy.y, viy.z, viy.w};
    const int dmr[4] = {vdm.x, vdm.y, vdm.z, vdm.w};
    const float scr[4] = {vsc.x, vsc.y, vsc.z, vsc.w};
    __syncthreads();

    // histogram; atomicAdd return value = in-bin rank
    int pk[4], pb[4], rk[4];
    float pv[4];
#pragma unroll
    for (int i = 0; i < 4; ++i) {
        pk[i] = (ixr[i] << 12) | iyr[i];
        pb[i] = ((ixr[i] >> 6) << 6) | (iyr[i] >> 6);
        pv[i] = scr[i] * u_t[dmr[i]];
        rk[i] = atomicAdd(&cnt[pb[i]], 1);
    }
    __syncthreads();

    // two-level exclusive prefix scan over 4096 bins (4 bins/thread)
    int loc[4], s = 0;
#pragma unroll
    for (int k = 0; k < 4; ++k) { loc[k] = cnt[t * 4 + k]; s += loc[k]; }
    const int lane = t & 63, wv = t >> 6;
    int x = s;
#pragma unroll
    for (int d = 1; d < 64; d <<= 1) {
        const int y = __shfl_up(x, d, 64);
        if (lane >= d) x += y;
    }
    if (lane == 63) wtot[wv] = x;
    __syncthreads();                          // orders loc reads vs start writes
    int run = x - s;
    for (int w = 0; w < wv; ++w) run += wtot[w];
#pragma unroll
    for (int k = 0; k < 4; ++k) { cnt[t * 4 + k] = run; run += loc[k]; }
    if (t == 0) cnt[4096] = N_INJ;
    __syncthreads();
    // cnt[bin] = START of bin; end(bin) = cnt[bin+1] (bins contiguous)

    // scatter: NO atomics (pos = start + rank)
#pragma unroll
    for (int i = 0; i < 4; ++i) {
        const int pos = cnt[pb[i]] + rk[i];
        spack[pos] = pk[i];
        sval[pos]  = pv[i];
    }
    __syncthreads();

    // measure: threads 0..255, one measurement each, 3x3 neighbor bins
    if (t < 256) {
        const int axlo = ((mx - 63) & WRAP_M) >> 6;
        const int aylo = ((my - 63) & WRAP_M) >> 6;
        float acc = 0.f;
#pragma unroll
        for (int r2 = 0; r2 < 3; ++r2) {
            const int base = ((axlo + r2) & 63) << 6;
            int s0[2], s1[2], nseg = 1;
            s0[0] = base + aylo;
            if (aylo <= 61) {
                s1[0] = base + aylo + 2;
            } else {                          // y-range wraps the bin row
                s1[0] = base + 63;
                s0[1] = base; s1[1] = base + (aylo - 62);
                nseg = 2;
            }
            for (int sg = 0; sg < nseg; ++sg) {
                const int lo = cnt[s0[sg]];
                const int hi = cnt[s1[sg] + 1];
                for (int p = lo; p < hi; ++p) {
                    const int sp = spack[p];
                    const int a  = (mx - (sp >> 12)) & WRAP_M;
                    const int c  = (my - (sp & WRAP_M)) & WRAP_M;
                    if ((((a + 63) & WRAP_M) < 127) && (((c + 63) & WRAP_M) < 127)) {
                        const int ax = min(a, 4096 - a);
                        const int ay = min(c, 4096 - c);
                        acc += sval[p] * KQ.r[ax].v[ay];
                    }
                }
            }
        }
        out[(b << 8) + t] = acc;
    }
}

extern "C" void kernel_launch(void* const* d_in, const int* in_sizes, int n_in,
                              void* d_out, int out_size, void* d_ws, size_t ws_size,
                              hipStream_t stream) {
    const float* u_t        = (const float*)d_in[0];
    const float* inj_scales = (const float*)d_in[1];
    const int*   inj_dims   = (const int*)d_in[2];
    const int*   inj_ix     = (const int*)d_in[3];
    const int*   inj_iy     = (const int*)d_in[4];
    const int*   meas_ix    = (const int*)d_in[5];
    const int*   meas_iy    = (const int*)d_in[6];
    float*       out        = (float*)d_out;

    hipLaunchKernelGGL(fused, dim3(16), dim3(1024), 0, stream,
                       u_t, inj_scales, inj_dims, inj_ix, inj_iy,
                       meas_ix, meas_iy, out);
}